// Round 1
// baseline (938.252 us; speedup 1.0000x reference)
//
#include <hip/hip_runtime.h>
#include <math.h>

#define NN 50000
#define EE 800000
#define IN_F 30
#define NH 8
#define DH 32
#define HD 256      // NH*DH
#define NG 512
#define NHID 128
#define ALPHA 0.2f
#define ENC_NEG_INF 0x007fffffu

// ---------- float <-> order-preserving unsigned encoding (for atomicMax) ----------
__device__ __forceinline__ unsigned encf(float x){
  unsigned u = __float_as_uint(x);
  return (u & 0x80000000u) ? ~u : (u | 0x80000000u);
}
__device__ __forceinline__ float decf(unsigned u){
  return (u & 0x80000000u) ? __uint_as_float(u & 0x7fffffffu) : __uint_as_float(~u);
}

// ---------- init: zero counts, zero gsum, set gmax to enc(-inf) ----------
__global__ void k_init(int* counts, float* gsum, unsigned* gmax){
  int i = blockIdx.x*blockDim.x + threadIdx.x;
  if(i < NN) counts[i] = 0;
  if(i < NG*DH){ gsum[i] = 0.f; gmax[i] = ENC_NEG_INF; }
}

// ---------- CSR build: histogram by dst ----------
__global__ void k_hist(const int* __restrict__ dst, int* counts){
  int i = blockIdx.x*blockDim.x + threadIdx.x;
  if(i < EE) atomicAdd(&counts[dst[i]], 1);
}

// ---------- single-block exclusive scan over counts -> start, cursor ----------
__global__ void k_scan(const int* __restrict__ counts, int* start, int* cursor){
  __shared__ int sd[1024];
  int t = threadIdx.x;
  const int CH = (NN + 1023)/1024;   // 49
  int base = t*CH;
  int sum = 0;
  for(int i=0;i<CH;i++){ int idx=base+i; if(idx<NN) sum += counts[idx]; }
  sd[t]=sum; __syncthreads();
  for(int off=1; off<1024; off<<=1){
    int v = (t>=off)? sd[t-off] : 0;
    __syncthreads();
    sd[t] += v;
    __syncthreads();
  }
  int run = sd[t]-sum;               // exclusive prefix
  for(int i=0;i<CH;i++){
    int idx=base+i;
    if(idx<NN){ start[idx]=run; cursor[idx]=run; run += counts[idx]; }
  }
}

// ---------- scatter edge ids into dst-grouped order ----------
__global__ void k_scatter(const int* __restrict__ dst, int* cursor, int* perm){
  int i = blockIdx.x*blockDim.x + threadIdx.x;
  if(i<EE){ int p = atomicAdd(&cursor[dst[i]],1); perm[p]=i; }
}

// ---------- layer-1 projection: feat = x(N,30) @ W1(30,256) ----------
#define TM1 32
__global__ void k_proj1(const float* __restrict__ x, const float* __restrict__ W1,
                        float* __restrict__ feat){
  __shared__ float xs[TM1][IN_F];
  int n0 = blockIdx.x*TM1;
  int j = threadIdx.x;                 // output column 0..255
  for(int i=j;i<TM1*IN_F;i+=256){
    int m=i/IN_F, k=i-m*IN_F;
    int n=n0+m;
    xs[m][k] = (n<NN)? x[(size_t)n*IN_F+k] : 0.f;
  }
  __syncthreads();
  float acc[TM1];
  #pragma unroll
  for(int m=0;m<TM1;m++) acc[m]=0.f;
  for(int k=0;k<IN_F;k++){
    float w = W1[k*HD+j];
    #pragma unroll
    for(int m=0;m<TM1;m++) acc[m] += xs[m][k]*w;
  }
  for(int m=0;m<TM1;m++){
    int n=n0+m;
    if(n<NN) feat[(size_t)n*HD+j] = acc[m];
  }
}

// ---------- layer-2 projection: feat2 = h1(N,256) @ W2(256,256) ----------
#define TM2 64
__global__ void k_proj2(const float* __restrict__ X, const float* __restrict__ W,
                        float* __restrict__ Y){
  __shared__ float xs[TM2][64];
  int n0 = blockIdx.x*TM2;
  int j = threadIdx.x;                 // output column
  float acc[TM2];
  #pragma unroll
  for(int m=0;m<TM2;m++) acc[m]=0.f;
  for(int k0=0;k0<HD;k0+=64){
    __syncthreads();
    for(int i=j;i<TM2*64;i+=256){
      int m=i>>6, kk=i&63;
      int n=n0+m;
      xs[m][kk] = (n<NN)? X[(size_t)n*HD + k0+kk] : 0.f;
    }
    __syncthreads();
    for(int kk0=0; kk0<64; kk0+=4){
      float w0 = W[(k0+kk0  )*HD+j];
      float w1 = W[(k0+kk0+1)*HD+j];
      float w2 = W[(k0+kk0+2)*HD+j];
      float w3 = W[(k0+kk0+3)*HD+j];
      #pragma unroll
      for(int m=0;m<TM2;m++){
        float4 xv = *(const float4*)&xs[m][kk0];
        acc[m] += xv.x*w0 + xv.y*w1 + xv.z*w2 + xv.w*w3;
      }
    }
  }
  for(int m=0;m<TM2;m++){
    int n=n0+m;
    if(n<NN) Y[(size_t)n*HD+j] = acc[m];
  }
}

// ---------- attention logits el/er per (node, head) ----------
__global__ void k_elr(const float* __restrict__ feat, const float* __restrict__ al,
                      const float* __restrict__ ar, float* __restrict__ el,
                      float* __restrict__ er){
  int i = blockIdx.x*blockDim.x + threadIdx.x;  // n*8+h
  if(i >= NN*NH) return;
  int h = i & 7;
  const float4* f4 = (const float4*)(feat + (size_t)i*DH);
  const float4* a4 = (const float4*)(al + h*DH);
  const float4* b4 = (const float4*)(ar + h*DH);
  float ea=0.f, eb=0.f;
  #pragma unroll
  for(int q=0;q<8;q++){
    float4 f=f4[q], a=a4[q], b=b4[q];
    ea += f.x*a.x + f.y*a.y + f.z*a.z + f.w*a.w;
    eb += f.x*b.x + f.y*b.y + f.z*b.z + f.w*b.w;
  }
  el[i]=ea; er[i]=eb;
}

// ---------- per-node online-softmax aggregation (one wave per node) ----------
__device__ __forceinline__ float4 gat_agg(int n, int lane,
    const float* __restrict__ feat, const float* __restrict__ el,
    const float* __restrict__ er, const int* __restrict__ start,
    const int* __restrict__ counts, const int* __restrict__ perm,
    const int* __restrict__ src){
  int h = lane>>3;                       // 8 lanes per head
  float erh = er[n*NH + h];
  float m = -INFINITY, s = 0.f;
  float4 acc; acc.x=acc.y=acc.z=acc.w=0.f;
  int st = start[n], cnt = counts[n];
  int sn_next = (cnt>0)? src[perm[st]] : 0;
  for(int i=0;i<cnt;i++){
    int sn = sn_next;
    if(i+1<cnt) sn_next = src[perm[st+i+1]];   // prefetch next src index
    float e = el[sn*NH+h] + erh;
    e = (e>0.f)? e : ALPHA*e;                  // LeakyReLU
    float nm = fmaxf(m,e);
    float sc = expf(m-nm);                     // first iter: exp(-inf)=0
    float p  = expf(e-nm);
    s = s*sc + p;
    const float4 f = *(const float4*)(feat + (size_t)sn*HD + (lane<<2));
    acc.x = acc.x*sc + p*f.x;
    acc.y = acc.y*sc + p*f.y;
    acc.z = acc.z*sc + p*f.z;
    acc.w = acc.w*sc + p*f.w;
    m = nm;
  }
  float inv = 1.f/fmaxf(s,1e-9f);
  acc.x*=inv; acc.y*=inv; acc.z*=inv; acc.w*=inv;
  return acc;
}

// ---------- layer 1 finalize: + b1 + x@resW1 (fused), ELU ----------
__global__ void k_gat1(const float* __restrict__ feat, const float* __restrict__ el,
    const float* __restrict__ er, const int* __restrict__ start,
    const int* __restrict__ counts, const int* __restrict__ perm,
    const int* __restrict__ src, const float* __restrict__ x,
    const float* __restrict__ resW1, const float* __restrict__ b1,
    float* __restrict__ h1){
  int n = blockIdx.x*4 + (threadIdx.x>>6);
  int lane = threadIdx.x & 63;
  if(n>=NN) return;
  float4 acc = gat_agg(n,lane,feat,el,er,start,counts,perm,src);
  int col = lane<<2;
  float4 r = *(const float4*)(b1+col);
  const float* xrow = x + (size_t)n*IN_F;
  #pragma unroll
  for(int k=0;k<IN_F;k++){
    float xv = xrow[k];                          // wave-uniform broadcast
    const float4 wv = *(const float4*)(resW1 + k*HD + col);
    r.x += xv*wv.x; r.y += xv*wv.y; r.z += xv*wv.z; r.w += xv*wv.w;
  }
  float4 o; float v;
  v = acc.x + r.x; o.x = (v>0.f)? v : expf(v)-1.f;
  v = acc.y + r.y; o.y = (v>0.f)? v : expf(v)-1.f;
  v = acc.z + r.z; o.z = (v>0.f)? v : expf(v)-1.f;
  v = acc.w + r.w; o.w = (v>0.f)? v : expf(v)-1.f;
  *(float4*)(h1 + (size_t)n*HD + col) = o;
}

// ---------- layer 2 finalize: + b2 + h1 residual, mean over heads ----------
__global__ void k_gat2(const float* __restrict__ feat, const float* __restrict__ el,
    const float* __restrict__ er, const int* __restrict__ start,
    const int* __restrict__ counts, const int* __restrict__ perm,
    const int* __restrict__ src, const float* __restrict__ h1,
    const float* __restrict__ b2, float* __restrict__ h2){
  int n = blockIdx.x*4 + (threadIdx.x>>6);
  int lane = threadIdx.x & 63;
  if(n>=NN) return;
  float4 acc = gat_agg(n,lane,feat,el,er,start,counts,perm,src);
  int col = lane<<2;
  const float4 b  = *(const float4*)(b2+col);
  const float4 hr = *(const float4*)(h1 + (size_t)n*HD + col);
  float4 t;
  t.x = acc.x+b.x+hr.x; t.y = acc.y+b.y+hr.y;
  t.z = acc.z+b.z+hr.z; t.w = acc.w+b.w+hr.w;
  // sum over the 8 heads: lanes with equal lane%8 (xor offsets 8,16,32)
  #pragma unroll
  for(int off=8; off<64; off<<=1){
    t.x += __shfl_xor(t.x, off, 64);
    t.y += __shfl_xor(t.y, off, 64);
    t.z += __shfl_xor(t.z, off, 64);
    t.w += __shfl_xor(t.w, off, 64);
  }
  if(lane<8){
    float4 o; o.x=t.x*0.125f; o.y=t.y*0.125f; o.z=t.z*0.125f; o.w=t.w*0.125f;
    *(float4*)(h2 + (size_t)n*DH + col) = o;
  }
}

// ---------- readout gate w = sigmoid(h2 @ Ww + bw) ----------
__global__ void k_gate(const float* __restrict__ h2, const float* __restrict__ Ww,
                       const float* __restrict__ bw, float* __restrict__ wgt){
  int n = blockIdx.x*blockDim.x + threadIdx.x;
  if(n>=NN) return;
  float acc = bw[0];
  const float4* hr = (const float4*)(h2 + (size_t)n*DH);
  const float4* w4 = (const float4*)Ww;
  #pragma unroll
  for(int q=0;q<8;q++){
    float4 h=hr[q], w=w4[q];
    acc += h.x*w.x + h.y*w.y + h.z*w.z + h.w*w.w;
  }
  wgt[n] = 1.f/(1.f+expf(-acc));
}

// ---------- graph readout: weighted sum + max via atomics ----------
__global__ void k_readout(const float* __restrict__ h2, const float* __restrict__ wgt,
    const int* __restrict__ gid, float* gsum, unsigned* gmax){
  int i = blockIdx.x*blockDim.x + threadIdx.x;   // n*32+d
  if(i>=NN*DH) return;
  int n = i>>5, d = i&31;
  int g = gid[n];
  float v = h2[i];
  atomicAdd(&gsum[g*DH+d], wgt[n]*v);
  atomicMax(&gmax[g*DH+d], encf(v));
}

// ---------- MLP predictor: one block (128 thr) per graph ----------
__global__ void k_mlp(const float* __restrict__ gsum, const unsigned* __restrict__ gmax,
    const float* __restrict__ Wp1, const float* __restrict__ bp1,
    const float* __restrict__ gamma, const float* __restrict__ beta,
    const float* __restrict__ rm, const float* __restrict__ rv,
    const float* __restrict__ Wp2, const float* __restrict__ bp2,
    float* __restrict__ out){
  __shared__ float gs[2*DH];
  __shared__ float red[NHID];
  int g = blockIdx.x, t = threadIdx.x;
  if(t < DH) gs[t] = gsum[g*DH + t];
  else if(t < 2*DH){
    unsigned u = gmax[g*DH + (t-DH)];
    gs[t] = (u==ENC_NEG_INF)? 0.f : decf(u);     // isfinite guard
  }
  __syncthreads();
  float acc = bp1[t];
  #pragma unroll
  for(int k=0;k<2*DH;k++) acc += gs[k]*Wp1[k*NHID + t];
  acc = fmaxf(acc, 0.f);
  acc = (acc - rm[t])*rsqrtf(rv[t]+1e-5f)*gamma[t] + beta[t];
  red[t] = acc*Wp2[t];
  __syncthreads();
  for(int off=NHID/2; off>0; off>>=1){
    if(t<off) red[t] += red[t+off];
    __syncthreads();
  }
  if(t==0) out[g] = red[0] + bp2[0];
}

extern "C" void kernel_launch(void* const* d_in, const int* in_sizes, int n_in,
                              void* d_out, int out_size, void* d_ws, size_t ws_size,
                              hipStream_t stream){
  const float* x    = (const float*)d_in[0];
  const int*   src  = (const int*)  d_in[1];
  const int*   dst  = (const int*)  d_in[2];
  const int*   gid  = (const int*)  d_in[3];
  const float* W1   = (const float*)d_in[4];
  const float* al1  = (const float*)d_in[5];
  const float* ar1  = (const float*)d_in[6];
  const float* b1   = (const float*)d_in[7];
  const float* resW1= (const float*)d_in[8];
  const float* W2   = (const float*)d_in[9];
  const float* al2  = (const float*)d_in[10];
  const float* ar2  = (const float*)d_in[11];
  const float* b2   = (const float*)d_in[12];
  const float* Ww   = (const float*)d_in[13];
  const float* bw   = (const float*)d_in[14];
  const float* Wp1  = (const float*)d_in[15];
  const float* bp1  = (const float*)d_in[16];
  const float* gamma= (const float*)d_in[17];
  const float* beta = (const float*)d_in[18];
  const float* rm   = (const float*)d_in[19];
  const float* rv   = (const float*)d_in[20];
  const float* Wp2  = (const float*)d_in[21];
  const float* bp2  = (const float*)d_in[22];
  float* out = (float*)d_out;

  char* w = (char*)d_ws;
  float*    feat  = (float*)w;    w += (size_t)NN*HD*4;   // feat1, then feat2
  float*    h1    = (float*)w;    w += (size_t)NN*HD*4;
  float*    el    = (float*)w;    w += (size_t)NN*NH*4;
  float*    er    = (float*)w;    w += (size_t)NN*NH*4;
  float*    h2    = (float*)w;    w += (size_t)NN*DH*4;
  float*    wgt   = (float*)w;    w += (size_t)NN*4;
  float*    gsum  = (float*)w;    w += (size_t)NG*DH*4;
  unsigned* gmax  = (unsigned*)w; w += (size_t)NG*DH*4;
  int*      counts= (int*)w;      w += (size_t)NN*4;
  int*      start = (int*)w;      w += (size_t)NN*4;
  int*      cursor= (int*)w;      w += (size_t)NN*4;
  int*      perm  = (int*)w;      w += (size_t)EE*4;

  hipLaunchKernelGGL(k_init,    dim3((NN+255)/256),      dim3(256),  0, stream, counts, gsum, gmax);
  hipLaunchKernelGGL(k_hist,    dim3((EE+255)/256),      dim3(256),  0, stream, dst, counts);
  hipLaunchKernelGGL(k_scan,    dim3(1),                 dim3(1024), 0, stream, counts, start, cursor);
  hipLaunchKernelGGL(k_scatter, dim3((EE+255)/256),      dim3(256),  0, stream, dst, cursor, perm);
  hipLaunchKernelGGL(k_proj1,   dim3((NN+TM1-1)/TM1),    dim3(256),  0, stream, x, W1, feat);
  hipLaunchKernelGGL(k_elr,     dim3((NN*NH+255)/256),   dim3(256),  0, stream, feat, al1, ar1, el, er);
  hipLaunchKernelGGL(k_gat1,    dim3((NN+3)/4),          dim3(256),  0, stream, feat, el, er, start, counts, perm, src, x, resW1, b1, h1);
  hipLaunchKernelGGL(k_proj2,   dim3((NN+TM2-1)/TM2),    dim3(256),  0, stream, h1, W2, feat);
  hipLaunchKernelGGL(k_elr,     dim3((NN*NH+255)/256),   dim3(256),  0, stream, feat, al2, ar2, el, er);
  hipLaunchKernelGGL(k_gat2,    dim3((NN+3)/4),          dim3(256),  0, stream, feat, el, er, start, counts, perm, src, h1, b2, h2);
  hipLaunchKernelGGL(k_gate,    dim3((NN+255)/256),      dim3(256),  0, stream, h2, Ww, bw, wgt);
  hipLaunchKernelGGL(k_readout, dim3((NN*DH+255)/256),   dim3(256),  0, stream, h2, wgt, gid, gsum, gmax);
  hipLaunchKernelGGL(k_mlp,     dim3(NG),                dim3(NHID), 0, stream, gsum, gmax, Wp1, bp1, gamma, beta, rm, rv, Wp2, bp2, out);
}